// Round 5
// baseline (2024.056 us; speedup 1.0000x reference)
//
#include <hip/hip_runtime.h>
#include <math.h>

#define N_NODES 8000
#define N_EDGES 256000
#define NSTEPS 10
#define LO_SCALE 4096.0f
#define LO_INV   (1.0f/4096.0f)

typedef unsigned short u16;
typedef unsigned int   u32;
typedef _Float16 h8_t __attribute__((ext_vector_type(8)));
typedef float f32x4 __attribute__((ext_vector_type(4)));

#define MFMA(a, b, c) __builtin_amdgcn_mfma_f32_16x16x32_f16((a), (b), (c), 0, 0, 0)

// x ~= hi + lo/4096, relative error ~2^-22 (lo scaled to stay fp16-normal)
__device__ __forceinline__ void split2(float x, u16& hi, u16& lo) {
    _Float16 h = (_Float16)x;
    _Float16 l = (_Float16)((x - (float)h) * LO_SCALE);
    hi = __builtin_bit_cast(u16, h);
    lo = __builtin_bit_cast(u16, l);
}
__device__ __forceinline__ float h2f(u16 u) {
    return (float)__builtin_bit_cast(_Float16, u);
}
__device__ __forceinline__ float joinv(u16 hi, u16 lo) {
    return h2f(hi) + h2f(lo) * LO_INV;
}
// packed u32: low16 = hi part, high16 = lo part
__device__ __forceinline__ float joinp(u32 u) {
    return h2f((u16)(u & 0xffffu)) + h2f((u16)(u >> 16)) * LO_INV;
}

union U8 { u16 s[8]; uint4 v; };

// ---------------- one-time prep kernels ----------------

// exg[e] = float4 {Jv, b[row], b[col], 0}; degf[r] += 1
__global__ __launch_bounds__(256)
void prep_edges_k(const float* __restrict__ J, const float* __restrict__ b,
                  const int* __restrict__ row, const int* __restrict__ col,
                  float4* __restrict__ exg, float* __restrict__ degf) {
    int idx = blockIdx.x * 256 + threadIdx.x;
    if (idx < N_EDGES) {
        int r = row[idx], c = col[idx];
        float4 v;
        v.x = J[(long)r * N_NODES + c];
        v.y = b[r];
        v.z = b[c];
        v.w = 0.f;
        exg[idx] = v;
        atomicAdd(&degf[r], 1.0f);
    }
}

// W2 pairs [128][128]; W1ab pairs [256][64] (rows 0..127 = W1a = Wm1[:, :64],
// rows 128..255 = W1b = Wm1[:, 64:128]); W3 pairs [64][128];
// extraW f32 [4][128] = {Wm1[:,128], Wm1[:,129], Wm1[:,130], bm1}
__global__ __launch_bounds__(256)
void convw_k(const float* __restrict__ Wm1, const float* __restrict__ bm1,
             const float* __restrict__ Wm2, const float* __restrict__ Wm3,
             u16* __restrict__ W2_h,  u16* __restrict__ W2_l,
             u16* __restrict__ Wab_h, u16* __restrict__ Wab_l,
             u16* __restrict__ W3_h,  u16* __restrict__ W3_l,
             float* __restrict__ extraW) {
    int i = blockIdx.x * 256 + threadIdx.x;
    u16 hi, lo;
    if (i < 16384) {                       // W2 [j][k]
        split2(Wm2[i], hi, lo);
        W2_h[i] = hi; W2_l[i] = lo;
    } else if (i < 32768) {                // W1ab [256][64]
        int t = i - 16384; int j = t >> 6, k = t & 63;
        float src = (j < 128) ? Wm1[j * 131 + k] : Wm1[(j - 128) * 131 + 64 + k];
        split2(src, hi, lo);
        Wab_h[t] = hi; Wab_l[t] = lo;
    } else if (i < 40960) {                // W3 [64][128]
        int t = i - 32768;
        split2(Wm3[t], hi, lo);
        W3_h[t] = hi; W3_l[t] = lo;
    } else if (i < 41472) {                // extraW
        int t = i - 40960; int rr = t >> 7, j = t & 127;
        extraW[t] = (rr < 3) ? Wm1[j * 131 + 128 + rr] : bm1[j];
    }
}

// out[k*O + j] = in[j*K + k]
__global__ __launch_bounds__(256)
void transpose_k(const float* __restrict__ in, float* __restrict__ out, int O, int K) {
    int idx = blockIdx.x * 256 + threadIdx.x;
    if (idx < O * K) {
        int j = idx / K, k = idx - j * K;
        out[k * O + j] = in[idx];
    }
}

// ---------------- shared pair-GEMM core (verified frag layout) ----------------
// A in LDS: rows of CH 8-u16 chunks, chunk c of row r at (r*CH + (c ^ (r&7)))*8.
// W in global: [j][K] row-major pairs, K = K0*32.
// accH = Ah*Wh (+bias), accC = Ah*Wl + Al*Wh; value = accH + accC/4096.
template <int NT, int K0, int CH>
__device__ __forceinline__ void layer_gemm3(const u16* Ah, const u16* Al,
                                            const u16* __restrict__ Wh,
                                            const u16* __restrict__ Wl,
                                            const float* __restrict__ bias,
                                            int wn, int l15, int g,
                                            f32x4 (&accH)[4][NT], f32x4 (&accC)[4][NT]) {
    #pragma unroll
    for (int jt = 0; jt < NT; jt++) {
        float bv = bias ? bias[wn + jt * 16 + l15] : 0.f;
        #pragma unroll
        for (int et = 0; et < 4; et++) {
            accH[et][jt] = f32x4{bv, bv, bv, bv};
            accC[et][jt] = f32x4{0.f, 0.f, 0.f, 0.f};
        }
    }
    #pragma unroll
    for (int k0 = 0; k0 < K0; k0++) {
        h8_t bh[NT], bl[NT], ah[4], al[4];
        #pragma unroll
        for (int jt = 0; jt < NT; jt++) {
            int off = (wn + jt * 16 + l15) * (K0 * 32) + k0 * 32 + g * 8;
            bh[jt] = *(const h8_t*)(Wh + off);
            bl[jt] = *(const h8_t*)(Wl + off);
        }
        #pragma unroll
        for (int et = 0; et < 4; et++) {
            int r = et * 16 + l15;
            int off = (r * CH + ((k0 * 4 + g) ^ (r & 7))) * 8;
            ah[et] = *(const h8_t*)(Ah + off);
            al[et] = *(const h8_t*)(Al + off);
        }
        #pragma unroll
        for (int et = 0; et < 4; et++)
            #pragma unroll
            for (int jt = 0; jt < NT; jt++) {
                accH[et][jt] = MFMA(ah[et], bh[jt], accH[et][jt]);
                accC[et][jt] = MFMA(ah[et], bl[jt], accC[et][jt]);
                accC[et][jt] = MFMA(al[et], bh[jt], accC[et][jt]);
            }
    }
}

// ---------------- edge kernel: t1 assembly + L2 GEMM + 128-dim scatter ----------------
__global__ __launch_bounds__(256)
void msg2_k(const u32* __restrict__ PQ,
            const int* __restrict__ row, const int* __restrict__ col,
            const float4* __restrict__ exg, const float* __restrict__ extraW,
            const u16* __restrict__ W2_h, const u16* __restrict__ W2_l,
            const float* __restrict__ bm2,
            float* __restrict__ nm2) {
    __shared__ u16 buf[2][64 * 128];      // t1 pairs; later aliased as t2 f32
    u16* Ah = buf[0];
    u16* Al = buf[1];
    const int tid  = threadIdx.x;
    const int e0   = blockIdx.x * 64;
    const int lane = tid & 63;
    const int w    = tid >> 6;
    const int l15  = lane & 15;
    const int g    = lane >> 4;

    // ---- t1[e][j] = P[row[e]][j] + Q[col[e]][j] + Jv*w128 + br*w129 + bc*w130 + bm1 ----
    {
        int e = tid >> 2, jq = tid & 3;          // 32 j's per thread
        int nr = row[e0 + e], nc = col[e0 + e];
        float4 ex = exg[e0 + e];
        const u32* Pp = PQ + nr * 256 + jq * 32;
        const u32* Qp = PQ + nc * 256 + 128 + jq * 32;
        #pragma unroll
        for (int cc = 0; cc < 4; cc++) {
            uint4 p0 = ((const uint4*)Pp)[cc * 2];
            uint4 p1 = ((const uint4*)Pp)[cc * 2 + 1];
            uint4 q0 = ((const uint4*)Qp)[cc * 2];
            uint4 q1 = ((const uint4*)Qp)[cc * 2 + 1];
            u32 pu[8] = {p0.x, p0.y, p0.z, p0.w, p1.x, p1.y, p1.z, p1.w};
            u32 qu[8] = {q0.x, q0.y, q0.z, q0.w, q1.x, q1.y, q1.z, q1.w};
            U8 uh, ul;
            #pragma unroll
            for (int m = 0; m < 8; m++) {
                int j = jq * 32 + cc * 8 + m;
                float v = joinp(pu[m]) + joinp(qu[m])
                        + ex.x * extraW[j] + ex.y * extraW[128 + j]
                        + ex.z * extraW[256 + j] + extraW[384 + j];
                v = fmaxf(v, 0.f);
                u16 hi, lo; split2(v, hi, lo);
                uh.s[m] = hi; ul.s[m] = lo;
            }
            int c = jq * 4 + cc;
            int dst = (e * 16 + (c ^ (e & 7))) * 8;
            *(uint4*)(Ah + dst) = uh.v;
            *(uint4*)(Al + dst) = ul.v;
        }
    }
    __syncthreads();

    // ---- layer 2: [128] -> [128], relu (pair GEMM) ----
    f32x4 accH[4][2], accC[4][2];
    layer_gemm3<2, 4, 16>(Ah, Al, W2_h, W2_l, bm2, w * 32, l15, g, accH, accC);
    __syncthreads();                       // all waves done reading t1 pairs

    float* t2 = (float*)buf;               // 64x128 f32 == 32 KB == all of buf
    #pragma unroll
    for (int et = 0; et < 4; et++)
        #pragma unroll
        for (int jt = 0; jt < 2; jt++) {
            int j = w * 32 + jt * 16 + l15;
            #pragma unroll
            for (int r = 0; r < 4; r++) {
                int e = et * 16 + g * 4 + r;
                t2[e * 128 + j] = fmaxf(accH[et][jt][r] + accC[et][jt][r] * LO_INV, 0.f);
            }
        }
    __syncthreads();

    // ---- scatter: rows sorted (np.unique) -> run-accumulate, few atomics ----
    {
        int d2 = tid & 127, q = tid >> 7;
        int ebeg = q * 32;
        float a = 0.f;
        int cur = row[e0 + ebeg];
        for (int e = ebeg; e < ebeg + 32; e++) {
            int rr = row[e0 + e];
            if (rr != cur) { atomicAdd(&nm2[cur * 128 + d2], a); a = 0.f; cur = rr; }
            a += t2[e * 128 + d2];
        }
        atomicAdd(&nm2[cur * 128 + d2], a);
    }
}

// ---------------- node kernel: nm = nm2 @ W3^T + deg*bm3 (consumes & zeros nm2) ----------------
__global__ __launch_bounds__(256)
void nodeL3_k(float* __restrict__ nm2, const float* __restrict__ degf,
              const u16* __restrict__ W3_h, const u16* __restrict__ W3_l,
              const float* __restrict__ bm3, float* __restrict__ nm) {
    __shared__ u16 Ah[64 * 128], Al[64 * 128];
    const int tid = threadIdx.x;
    const int n0  = blockIdx.x * 64;
    const int lane = tid & 63, w = tid >> 6, l15 = lane & 15, g = lane >> 4;

    {
        int n = tid >> 2, kq = tid & 3;
        float* src = nm2 + (n0 + n) * 128 + kq * 32;
        #pragma unroll
        for (int cc = 0; cc < 4; cc++) {
            U8 uh, ul;
            #pragma unroll
            for (int m = 0; m < 8; m++) {
                u16 hi, lo; split2(src[cc * 8 + m], hi, lo);
                uh.s[m] = hi; ul.s[m] = lo;
            }
            int c = kq * 4 + cc;
            int dst = (n * 16 + (c ^ (n & 7))) * 8;
            *(uint4*)(Ah + dst) = uh.v;
            *(uint4*)(Al + dst) = ul.v;
        }
        #pragma unroll
        for (int m = 0; m < 8; m++)
            ((f32x4*)src)[m] = f32x4{0.f, 0.f, 0.f, 0.f};   // clear for next step
    }
    __syncthreads();

    f32x4 accH[4][1], accC[4][1];
    layer_gemm3<1, 4, 16>(Ah, Al, W3_h, W3_l, (const float*)nullptr, w * 16, l15, g, accH, accC);

    int j = w * 16 + l15;
    float bj = bm3[j];
    #pragma unroll
    for (int et = 0; et < 4; et++)
        #pragma unroll
        for (int r = 0; r < 4; r++) {
            int n = et * 16 + g * 4 + r;
            nm[(n0 + n) * 64 + j] = accH[et][0][r] + accC[et][0][r] * LO_INV
                                  + degf[n0 + n] * bj;
        }
}

// ---------------- node kernel: PQ = h @ [W1a|W1b]^T (pair GEMM, packed output) ----------------
__global__ __launch_bounds__(256)
void embed_k(const u16* __restrict__ h_hi, const u16* __restrict__ h_lo,
             const u16* __restrict__ Wab_h, const u16* __restrict__ Wab_l,
             u32* __restrict__ PQ) {
    __shared__ u16 Ah[64 * 64], Al[64 * 64];
    const int tid = threadIdx.x;
    const int n0  = blockIdx.x * 64;
    const int lane = tid & 63, w = tid >> 6, l15 = lane & 15, g = lane >> 4;

    {
        int n = tid >> 2, seg = tid & 3;
        #pragma unroll
        for (int cc = 0; cc < 2; cc++) {
            int c = seg * 2 + cc;
            int dst = (n * 8 + (c ^ (n & 7))) * 8;
            *(uint4*)(Ah + dst) = *(const uint4*)(h_hi + (n0 + n) * 64 + c * 8);
            *(uint4*)(Al + dst) = *(const uint4*)(h_lo + (n0 + n) * 64 + c * 8);
        }
    }
    __syncthreads();

    f32x4 accH[4][4], accC[4][4];
    layer_gemm3<4, 2, 8>(Ah, Al, Wab_h, Wab_l, (const float*)nullptr, w * 64, l15, g, accH, accC);

    #pragma unroll
    for (int et = 0; et < 4; et++)
        #pragma unroll
        for (int jt = 0; jt < 4; jt++) {
            int j = w * 64 + jt * 16 + l15;
            #pragma unroll
            for (int r = 0; r < 4; r++) {
                int n = et * 16 + g * 4 + r;
                float v = accH[et][jt][r] + accC[et][jt][r] * LO_INV;
                u16 hi, lo; split2(v, hi, lo);
                PQ[(n0 + n) * 256 + j] = (u32)hi | ((u32)lo << 16);
            }
        }
}

// ---------------- GRU (fp32 math, h kept as fp16 hi/lo pair) ----------------
__global__ __launch_bounds__(256)
void gru_k(const float* __restrict__ nm,
           u16* __restrict__ h_hi, u16* __restrict__ h_lo,
           const float* __restrict__ Wiht, const float* __restrict__ Whht,
           const float* __restrict__ b_ih, const float* __restrict__ b_hh) {
    __shared__ float nms[4][64], hs[4][64];
    int tid = threadIdx.x, g = tid >> 6, d = tid & 63;
    int n = blockIdx.x * 4 + g;
    nms[g][d] = nm[n * 64 + d];
    hs[g][d]  = joinv(h_hi[n * 64 + d], h_lo[n * 64 + d]);
    __syncthreads();
    float ir = b_ih[d], iz = b_ih[64 + d], inn = b_ih[128 + d];
    float hr = b_hh[d], hz = b_hh[64 + d], hnn = b_hh[128 + d];
    for (int k = 0; k < 64; k++) {
        float nv = nms[g][k], hv = hs[g][k];
        const float* wi = Wiht + k * 192;
        const float* wh = Whht + k * 192;
        ir  = fmaf(nv, wi[d],       ir);
        iz  = fmaf(nv, wi[64 + d],  iz);
        inn = fmaf(nv, wi[128 + d], inn);
        hr  = fmaf(hv, wh[d],       hr);
        hz  = fmaf(hv, wh[64 + d],  hz);
        hnn = fmaf(hv, wh[128 + d], hnn);
    }
    float r  = 1.f / (1.f + expf(-(ir + hr)));
    float z  = 1.f / (1.f + expf(-(iz + hz)));
    float ng = tanhf(inn + r * hnn);
    float v  = (1.f - z) * ng + z * hs[g][d];
    u16 hi, lo; split2(v, hi, lo);
    h_hi[n * 64 + d] = hi;
    h_lo[n * 64 + d] = lo;
}

// ---------------- readout MLP + softmax ----------------
__global__ __launch_bounds__(256)
void readout_k(const u16* __restrict__ h_hi, const u16* __restrict__ h_lo,
               const float* __restrict__ Wr1t, const float* __restrict__ br1,
               const float* __restrict__ Wr2t, const float* __restrict__ br2,
               const float* __restrict__ Wr3,  const float* __restrict__ br3,
               float* __restrict__ out) {
    __shared__ float hs[4][64], r1s[4][128];
    int tid = threadIdx.x, g = tid >> 6, d = tid & 63;
    int n = blockIdx.x * 4 + g;
    hs[g][d] = joinv(h_hi[n * 64 + d], h_lo[n * 64 + d]);
    __syncthreads();
    float a0 = br1[d], a1 = br1[64 + d];
    for (int k = 0; k < 64; k++) {
        float v = hs[g][k];
        a0 = fmaf(v, Wr1t[k * 128 + d],      a0);
        a1 = fmaf(v, Wr1t[k * 128 + 64 + d], a1);
    }
    r1s[g][d] = fmaxf(a0, 0.f); r1s[g][64 + d] = fmaxf(a1, 0.f);
    __syncthreads();
    a0 = br2[d]; a1 = br2[64 + d];
    for (int k = 0; k < 128; k++) {
        float v = r1s[g][k];
        a0 = fmaf(v, Wr2t[k * 128 + d],      a0);
        a1 = fmaf(v, Wr2t[k * 128 + 64 + d], a1);
    }
    float q0 = fmaxf(a0, 0.f), q1 = fmaxf(a1, 0.f);
    float p0 = q0 * Wr3[d]       + q1 * Wr3[64 + d];
    float p1 = q0 * Wr3[128 + d] + q1 * Wr3[128 + 64 + d];
    #pragma unroll
    for (int off = 32; off > 0; off >>= 1) {
        p0 += __shfl_down(p0, off);
        p1 += __shfl_down(p1, off);
    }
    if (d == 0) {
        float l0 = p0 + br3[0], l1 = p1 + br3[1];
        float mx = fmaxf(l0, l1);
        float e0v = expf(l0 - mx), e1v = expf(l1 - mx), s = e0v + e1v;
        out[n * 2 + 0] = e0v / s;
        out[n * 2 + 1] = e1v / s;
        out[2 * N_NODES + n * 2 + 0] = l0;
        out[2 * N_NODES + n * 2 + 1] = l1;
    }
}

extern "C" void kernel_launch(void* const* d_in, const int* in_sizes, int n_in,
                              void* d_out, int out_size, void* d_ws, size_t ws_size,
                              hipStream_t stream) {
    const float* J    = (const float*)d_in[0];
    const float* b    = (const float*)d_in[1];
    const int*   row  = (const int*)d_in[2];
    const int*   col  = (const int*)d_in[3];
    const float* Wm1  = (const float*)d_in[4];
    const float* bm1  = (const float*)d_in[5];
    const float* Wm2  = (const float*)d_in[6];
    const float* bm2  = (const float*)d_in[7];
    const float* Wm3  = (const float*)d_in[8];
    const float* bm3  = (const float*)d_in[9];
    const float* W_ih = (const float*)d_in[10];
    const float* W_hh = (const float*)d_in[11];
    const float* b_ih = (const float*)d_in[12];
    const float* b_hh = (const float*)d_in[13];
    const float* Wr1  = (const float*)d_in[14];
    const float* br1  = (const float*)d_in[15];
    const float* Wr2  = (const float*)d_in[16];
    const float* br2  = (const float*)d_in[17];
    const float* Wr3  = (const float*)d_in[18];
    const float* br3  = (const float*)d_in[19];
    float* out = (float*)d_out;

    // fp32 regions
    float* ws     = (float*)d_ws;
    float* nm     = ws;  ws += N_NODES * 64;
    float* nm2    = ws;  ws += N_NODES * 128;
    float* Wiht   = ws;  ws += 64 * 192;
    float* Whht   = ws;  ws += 64 * 192;
    float* Wr1t   = ws;  ws += 64 * 128;
    float* Wr2t   = ws;  ws += 128 * 128;
    float* extraW = ws;  ws += 4 * 128;
    float* degf   = ws;  ws += N_NODES;
    float* exg    = ws;  ws += N_EDGES * 4;      // float4
    u32*   PQ     = (u32*)ws;  ws += N_NODES * 256;
    // fp16-pair regions (u16 storage)
    u16* us    = (u16*)ws;
    u16* h_hi  = us;  us += N_NODES * 64;
    u16* h_lo  = us;  us += N_NODES * 64;
    u16* W2_h  = us;  us += 128 * 128;
    u16* W2_l  = us;  us += 128 * 128;
    u16* Wab_h = us;  us += 256 * 64;
    u16* Wab_l = us;  us += 256 * 64;
    u16* W3_h  = us;  us += 64 * 128;
    u16* W3_l  = us;  us += 64 * 128;

    hipMemsetAsync(degf, 0, N_NODES * sizeof(float), stream);
    prep_edges_k<<<(N_EDGES + 255) / 256, 256, 0, stream>>>(J, b, row, col,
                                                            (float4*)exg, degf);
    convw_k<<<162, 256, 0, stream>>>(Wm1, bm1, Wm2, Wm3, W2_h, W2_l,
                                     Wab_h, Wab_l, W3_h, W3_l, extraW);
    transpose_k<<<(192 * 64 + 255) / 256, 256, 0, stream>>>(W_ih, Wiht, 192, 64);
    transpose_k<<<(192 * 64 + 255) / 256, 256, 0, stream>>>(W_hh, Whht, 192, 64);
    transpose_k<<<(128 * 64 + 255) / 256, 256, 0, stream>>>(Wr1, Wr1t, 128, 64);
    transpose_k<<<(128 * 128 + 255) / 256, 256, 0, stream>>>(Wr2, Wr2t, 128, 128);

    hipMemsetAsync(h_hi, 0, N_NODES * 64 * sizeof(u16), stream);
    hipMemsetAsync(h_lo, 0, N_NODES * 64 * sizeof(u16), stream);
    hipMemsetAsync(PQ, 0, N_NODES * 256 * sizeof(u32), stream);   // embed(h=0)=0
    hipMemsetAsync(nm2, 0, N_NODES * 128 * sizeof(float), stream);

    for (int s = 0; s < NSTEPS; s++) {
        msg2_k<<<N_EDGES / 64, 256, 0, stream>>>(PQ, row, col, (const float4*)exg,
                                                 extraW, W2_h, W2_l, bm2, nm2);
        nodeL3_k<<<N_NODES / 64, 256, 0, stream>>>(nm2, degf, W3_h, W3_l, bm3, nm);
        gru_k<<<N_NODES / 4, 256, 0, stream>>>(nm, h_hi, h_lo, Wiht, Whht, b_ih, b_hh);
        embed_k<<<N_NODES / 64, 256, 0, stream>>>(h_hi, h_lo, Wab_h, Wab_l, PQ);
    }
    readout_k<<<N_NODES / 4, 256, 0, stream>>>(h_hi, h_lo, Wr1t, br1, Wr2t, br2,
                                               Wr3, br3, out);
}